// Round 1
// baseline (115.398 us; speedup 1.0000x reference)
//
#include <hip/hip_runtime.h>

// Problem constants (fixed by setup_inputs in the reference)
#define B_  8
#define T_  2048
#define D_  1024
#define H_  8
#define S_  128

// --------------------------------------------------------------------------
// FUSED kernel: one block per span (B*S = 1024 blocks, 512 threads).
// Rationale (R8): rocprof top-5 showed the timed window dominated by
// 256 MiB d_ws poison fills (2 x 41.3 us); kernels are only ~26 us. Fusing
// eliminates d_ws entirely AND removes K1's separate 64 MB features pass:
//   - Phase 1: stage kw into 32 KB LDS (K1 pattern); wave w computes logits
//     for span rows w, w+8, ... (< width) with the proven value-compacting
//     shuffle reduce. Each span row is read from HBM exactly once (~66 KB
//     avg per block -> ~68 MB total vs ~150 MB for the 2-kernel version).
//   - Phase 2: wave 0 runs the proven register softmax over the 256-float
//     logit slab (lane l holds idx 4l..4l+3, idx = r*8+h; parity-preserving
//     shfl_xor over {2,4,8,16,32}; idx >= width*8 masked -> weight exact 0).
//   - Phase 3: thread t owns cols t and t+512; k-loop over width rows,
//     weights are wave-uniform LDS broadcasts, feat re-reads hit L2 (rows
//     were just loaded by this block on this CU).
// LDS 33 KB -> 4 blocks/CU cap; no cross-iteration prefetch to keep VGPRs
// low (target <=64 for 8 waves/SIMD). d_ws is untouched.
// --------------------------------------------------------------------------
__global__ __launch_bounds__(512) void span_pool_kernel(
    const float* __restrict__ feat,    // [B*T, D]
    const int* __restrict__ begins,    // [B*S]
    const int* __restrict__ ends,      // [B*S]
    const float* __restrict__ kw,      // [H, D]
    const float* __restrict__ kb,      // [H]
    float* __restrict__ out)           // [B*S, D]
{
    const int bs   = blockIdx.x;            // span id 0..1023
    const int b    = bs >> 7;               // / S_
    const int wv   = threadIdx.x >> 6;      // 0..7
    const int lane = threadIdx.x & 63;

    __shared__ __align__(16) float kwl[H_ * D_];   // 32 KB staged key_w
    __shared__ __align__(16) float wts[32 * H_];   // logits -> weights, 1 KB

    {   // stage kw: 512 threads x 4 float4 (coalesced, L2-hot after blk 0)
        const float4* src = (const float4*)kw;
        float4*       dst = (float4*)kwl;
        dst[threadIdx.x]        = src[threadIdx.x];
        dst[threadIdx.x + 512]  = src[threadIdx.x + 512];
        dst[threadIdx.x + 1024] = src[threadIdx.x + 1024];
        dst[threadIdx.x + 1536] = src[threadIdx.x + 1536];
    }

    const int begin = begins[bs];
    const int width = ends[bs] - begin;     // 1..32, rows always in-bounds
    const size_t row0 = (size_t)b * T_ + begin;
    const float kbv = (lane < H_) ? kb[lane] : 0.f;

    // First row load issued BEFORE the barrier (independent of LDS staging).
    float4 fv0, fv1, fv2, fv3;
    const int r0 = wv;
    if (r0 < width) {
        const float* fr = feat + (row0 + r0) * D_ + lane * 4;
        fv0 = *(const float4*)(fr +   0);
        fv1 = *(const float4*)(fr + 256);
        fv2 = *(const float4*)(fr + 512);
        fv3 = *(const float4*)(fr + 768);
    }
    __syncthreads();

    // ---- Phase 1: logits for rows wv, wv+8, wv+16, wv+24 (while < width)
    for (int r = r0; r < width; r += 8) {
        if (r != r0) {
            const float* fr = feat + (row0 + r) * D_ + lane * 4;
            fv0 = *(const float4*)(fr +   0);
            fv1 = *(const float4*)(fr + 256);
            fv2 = *(const float4*)(fr + 512);
            fv3 = *(const float4*)(fr + 768);
        }
        float acc[H_];
#pragma unroll
        for (int h = 0; h < H_; ++h) {
            const float* kh = &kwl[h * D_ + lane * 4];
            float4 k0 = *(const float4*)(kh +   0);
            float4 k1 = *(const float4*)(kh + 256);
            float4 k2 = *(const float4*)(kh + 512);
            float4 k3 = *(const float4*)(kh + 768);
            acc[h] = fv0.x * k0.x + fv0.y * k0.y + fv0.z * k0.z + fv0.w * k0.w
                   + fv1.x * k1.x + fv1.y * k1.y + fv1.z * k1.z + fv1.w * k1.w
                   + fv2.x * k2.x + fv2.y * k2.y + fv2.z * k2.z + fv2.w * k2.w
                   + fv3.x * k3.x + fv3.y * k3.y + fv3.z * k3.z + fv3.w * k3.w;
        }
        // Value-compacting reduce over lane bits 0..2 (proven in K1)
#pragma unroll
        for (int s = 0; s < 3; ++s) {
            const int m = 1 << s;
            const bool hi = (lane >> s) & 1;
#pragma unroll
            for (int j = 0; j < (4 >> s); ++j) {
                float mine  = hi ? acc[2 * j + 1] : acc[2 * j];
                float other = hi ? acc[2 * j]     : acc[2 * j + 1];
                acc[j] = mine + __shfl_xor(other, m, 64);
            }
        }
        acc[0] += __shfl_xor(acc[0],  8, 64);
        acc[0] += __shfl_xor(acc[0], 16, 64);
        acc[0] += __shfl_xor(acc[0], 32, 64);

        if (lane < H_)
            wts[r * H_ + lane] = acc[0] + kbv;
    }
    __syncthreads();

    // ---- Phase 2: wave 0 softmax over the span's logit slab (in place).
    // Same-head entries sit at idx == h (mod 8): lane bits 1..5 index rows,
    // so xor over {2,4,8,16,32} reduces within a head. (proven in K2)
    if (threadIdx.x < 64) {
        float4 lv = *(const float4*)&wts[lane * 4];
        const int w8 = width * H_;
        float v0 = (4 * lane + 0 < w8) ? lv.x : -1e30f;
        float v1 = (4 * lane + 1 < w8) ? lv.y : -1e30f;
        float v2 = (4 * lane + 2 < w8) ? lv.z : -1e30f;
        float v3 = (4 * lane + 3 < w8) ? lv.w : -1e30f;

        float m0 = v0, m1 = v1, m2 = v2, m3 = v3;
#pragma unroll
        for (int off = 2; off <= 32; off <<= 1) {
            m0 = fmaxf(m0, __shfl_xor(m0, off, 64));
            m1 = fmaxf(m1, __shfl_xor(m1, off, 64));
            m2 = fmaxf(m2, __shfl_xor(m2, off, 64));
            m3 = fmaxf(m3, __shfl_xor(m3, off, 64));
        }
        float e0 = __expf(v0 - m0);          // masked -> exactly 0
        float e1 = __expf(v1 - m1);
        float e2 = __expf(v2 - m2);
        float e3 = __expf(v3 - m3);
        float s0 = e0, s1 = e1, s2 = e2, s3 = e3;
#pragma unroll
        for (int off = 2; off <= 32; off <<= 1) {
            s0 += __shfl_xor(s0, off, 64);
            s1 += __shfl_xor(s1, off, 64);
            s2 += __shfl_xor(s2, off, 64);
            s3 += __shfl_xor(s3, off, 64);
        }
        *(float4*)&wts[lane * 4] =
            make_float4(e0 / s0, e1 / s1, e2 / s2, e3 / s3);
    }
    __syncthreads();

    // ---- Phase 3: pooled output. Thread t owns cols t and t+512.
    // Weight reads are wave-uniform (64-col wave span lies inside one
    // 128-col head) -> LDS broadcast, conflict-free. feat rows are L2-hot.
    const int c  = threadIdx.x;
    const int h0 = c >> 7;                  // head for col c; col c+512 -> h0+4
    const float* fb = feat + row0 * D_;
    float a0 = 0.f, a1 = 0.f;
    for (int k = 0; k < width; ++k) {
        const float* frw = fb + (size_t)k * D_;
        const float w0 = wts[k * H_ + h0];
        const float w1 = wts[k * H_ + h0 + 4];
        a0 += w0 * frw[c];
        a1 += w1 * frw[c + 512];
    }
    out[(size_t)bs * D_ + c]       = a0;
    out[(size_t)bs * D_ + c + 512] = a1;
}

extern "C" void kernel_launch(void* const* d_in, const int* in_sizes, int n_in,
                              void* d_out, int out_size, void* d_ws, size_t ws_size,
                              hipStream_t stream) {
    const float* feat   = (const float*)d_in[0];   // features f32 [B,T,D]
    const int*   begins = (const int*)d_in[1];     // int32 [B,S]
    const int*   ends   = (const int*)d_in[2];     // int32 [B,S]
    const float* kw     = (const float*)d_in[3];   // key_w f32 [H,D]
    const float* kb     = (const float*)d_in[4];   // key_b f32 [H]
    float*       out    = (float*)d_out;           // f32 [B*S, D]
    (void)d_ws; (void)ws_size;                     // workspace intentionally unused

    span_pool_kernel<<<B_ * S_, 512, 0, stream>>>(feat, begins, ends, kw, kb, out);
}